// Round 1
// baseline (428.938 us; speedup 1.0000x reference)
//
#include <hip/hip_runtime.h>
#include <stdint.h>

#define H 4096
#define KSEL 410
#define NT 256

__device__ __forceinline__ uint32_t absbits(float f) {
  return __float_as_uint(f) & 0x7fffffffu;
}

// One MSB-first radix-select round over WIDTH bits at SHIFT.
// On entry: target (K-th largest) is the k-th largest among elements whose
// bits above (SHIFT+WIDTH) equal `prefix`. On exit prefix/k are refined.
template <int SHIFT, int WIDTH, int LOG_PER>
__device__ __forceinline__ void select_round(
    const uint32_t* __restrict__ u,  // 16 abs-bit values per thread
    uint32_t* hist, uint32_t* aux,
    uint32_t* s_bin, uint32_t* s_k, uint32_t* s_cnt,
    uint32_t& prefix, uint32_t& k, const int tid) {
  constexpr int NB = 1 << WIDTH;
  constexpr int PER = NB / NT;
  static_assert(PER == (1 << LOG_PER), "per mismatch");
  constexpr int HI = SHIFT + WIDTH;                  // bits above this field
  constexpr int PSIZE = NB + (NB >> LOG_PER);        // padded layout size

  for (int b = tid; b < PSIZE; b += NT) hist[b] = 0;
  __syncthreads();

  #pragma unroll
  for (int j = 0; j < 16; ++j) {
    const uint32_t uj = u[j];
    if ((uj >> HI) == prefix) {
      const uint32_t b = (uj >> SHIFT) & (NB - 1);
      atomicAdd(&hist[b + (b >> LOG_PER)], 1u);      // padded: conflict-spread
    }
  }
  __syncthreads();

  // local suffix sums over my PER contiguous bins (stride PER+1 -> no bank conflicts)
  uint32_t loc[PER];
  {
    uint32_t sum = 0;
    #pragma unroll
    for (int j = PER - 1; j >= 0; --j) {
      sum += hist[tid * (PER + 1) + j];
      loc[j] = sum;
    }
    aux[tid] = sum;
  }
  __syncthreads();

  // wave 0: replace aux[t] with sum over all t' > t (suffix-exclusive)
  if (tid < 64) {
    uint4 a = ((const uint4*)aux)[tid];
    const uint32_t lsum = a.x + a.y + a.z + a.w;
    uint32_t s = lsum;
    #pragma unroll
    for (int off = 1; off < 64; off <<= 1) {
      uint32_t t = __shfl_down(s, off, 64);
      if (tid + off < 64) s += t;
    }
    const uint32_t above = s - lsum;                 // strictly-above lanes
    uint4 o;
    o.x = above + a.y + a.z + a.w;
    o.y = above + a.z + a.w;
    o.z = above + a.w;
    o.w = above;
    ((uint4*)aux)[tid] = o;
  }
  __syncthreads();

  // find the bin whose suffix range crosses rank k (exactly one thread hits)
  {
    const uint32_t above_t = aux[tid];
    #pragma unroll
    for (int j = 0; j < PER; ++j) {
      const uint32_t s_incl = above_t + loc[j];
      const uint32_t s_abv = (j + 1 < PER) ? (above_t + loc[j + 1]) : above_t;
      if (s_incl >= k && s_abv < k) {
        *s_bin = (uint32_t)(tid * PER + j);
        *s_k = k - s_abv;
        *s_cnt = s_incl - s_abv;                     // size of selected class
      }
    }
  }
  __syncthreads();
  prefix = (prefix << WIDTH) | *s_bin;
  k = *s_k;
}

__global__ __launch_bounds__(NT) void topk_select_kernel(
    const float* __restrict__ x, float* __restrict__ out) {
  __shared__ uint32_t hist[2304];   // padded 2048-bin round fits exactly
  __shared__ uint32_t aux[NT];
  __shared__ uint32_t s_bin, s_k, s_cnt;

  const int tid = threadIdx.x;
  const size_t base = (size_t)blockIdx.x * H;
  const float4* __restrict__ xr = (const float4*)(x + base);

  // coalesced load: thread t owns float4s {t, t+256, t+512, t+768}
  float4 r[4];
  #pragma unroll
  for (int j = 0; j < 4; ++j) r[j] = xr[tid + j * NT];

  uint32_t u[16];
  #pragma unroll
  for (int j = 0; j < 4; ++j) {
    u[4 * j + 0] = absbits(r[j].x);
    u[4 * j + 1] = absbits(r[j].y);
    u[4 * j + 2] = absbits(r[j].z);
    u[4 * j + 3] = absbits(r[j].w);
  }

  uint32_t prefix = 0, k = KSEL;
  select_round<20, 11, 3>(u, hist, aux, &s_bin, &s_k, &s_cnt, prefix, k, tid);
  select_round<10, 10, 2>(u, hist, aux, &s_bin, &s_k, &s_cnt, prefix, k, tid);
  select_round< 0, 10, 2>(u, hist, aux, &s_bin, &s_k, &s_cnt, prefix, k, tid);

  const uint32_t tbits = prefix;     // exact K-th largest |x| bit pattern
  const uint32_t keep_eq = k;        // how many ==tbits to keep (index order)
  const uint32_t cnt_eq = s_cnt;     // how many ==tbits exist

  uint32_t cut = H;                  // default: keep every equal element
  if (cnt_eq != keep_eq) {
    // rare exact tie at the boundary: find index of the keep_eq-th equal
    __syncthreads();                 // drain prior s_bin readers
    if (tid == 0) {
      const float* xs = x + base;
      uint32_t c = 0, ct = H;
      for (int i = 0; i < H; ++i) {
        if (absbits(xs[i]) == tbits) {
          if (++c == keep_eq) { ct = (uint32_t)i; break; }
        }
      }
      s_bin = ct;
    }
    __syncthreads();
    cut = s_bin;
  }

  float4* __restrict__ outr = (float4*)(out + base);
  #pragma unroll
  for (int j = 0; j < 4; ++j) {
    const float4 v = r[j];
    const uint32_t i0 = 4u * (uint32_t)(tid + j * NT);
    float4 o;
    o.x = (u[4*j+0] > tbits || (u[4*j+0] == tbits && i0 + 0u <= cut)) ? v.x : 0.0f;
    o.y = (u[4*j+1] > tbits || (u[4*j+1] == tbits && i0 + 1u <= cut)) ? v.y : 0.0f;
    o.z = (u[4*j+2] > tbits || (u[4*j+2] == tbits && i0 + 2u <= cut)) ? v.z : 0.0f;
    o.w = (u[4*j+3] > tbits || (u[4*j+3] == tbits && i0 + 3u <= cut)) ? v.w : 0.0f;
    outr[tid + j * NT] = o;
  }
}

extern "C" void kernel_launch(void* const* d_in, const int* in_sizes, int n_in,
                              void* d_out, int out_size, void* d_ws, size_t ws_size,
                              hipStream_t stream) {
  const float* x = (const float*)d_in[0];
  float* out = (float*)d_out;
  const int rows = in_sizes[0] / H;   // 16384
  hipLaunchKernelGGL(topk_select_kernel, dim3(rows), dim3(NT), 0, stream, x, out);
}